// Round 1
// baseline (1687.192 us; speedup 1.0000x reference)
//
#include <hip/hip_runtime.h>
#include <cstdint>
#include <cstddef>

#define N_NODES 4096
#define FDIM 256

#define BM 64
#define BN 64
#define BK 16

// ---------------- wave reduction helpers (wave = 64 lanes) ----------------
__device__ __forceinline__ float wave_reduce_sum(float v) {
#pragma unroll
  for (int off = 32; off >= 1; off >>= 1) v += __shfl_xor(v, off);
  return v;
}
__device__ __forceinline__ float wave_reduce_max(float v) {
#pragma unroll
  for (int off = 32; off >= 1; off >>= 1) v = fmaxf(v, __shfl_xor(v, off));
  return v;
}

// ---------------- row normalization: LayerNorm(h) and L1-normalize(x) -----
__global__ __launch_bounds__(256) void rownorm_kernel(
    const float* __restrict__ h, const float* __restrict__ x,
    const float* __restrict__ gamma, const float* __restrict__ beta,
    float* __restrict__ hn, float* __restrict__ xn) {
  __shared__ float redA[4], redB[4], redC[4];
  const int r = blockIdx.x;
  const int t = threadIdx.x;
  const size_t base = (size_t)r * FDIM + t;
  const float hv = h[base];
  const float xv = x[base];
  const int wid = t >> 6, lane = t & 63;

  float s1 = wave_reduce_sum(hv);
  float s2 = wave_reduce_sum(hv * hv);
  if (lane == 0) { redA[wid] = s1; redB[wid] = s2; }
  float a1 = wave_reduce_sum(fabsf(xv));
  if (lane == 0) redC[wid] = a1;
  __syncthreads();
  const float S1 = redA[0] + redA[1] + redA[2] + redA[3];
  const float S2 = redB[0] + redB[1] + redB[2] + redB[3];
  const float L1 = redC[0] + redC[1] + redC[2] + redC[3];
  const float mu = S1 * (1.0f / FDIM);
  const float var = S2 * (1.0f / FDIM) - mu * mu;
  const float rstd = rsqrtf(var + 1e-5f);
  hn[base] = (hv - mu) * rstd * gamma[t] + beta[t];
  xn[base] = xv / fmaxf(L1, 1e-12f);
}

// ---------------- generic tiled fp32 GEMM --------------------------------
// C[i][j] = alpha * sum_k opA(i,k)*opB(j,k)   (+ optional elu, + residual)
// TA=0: opA(i,k)=A[i*lda+k]; TA=1: opA(i,k)=A[k*lda+i]
// TB=1: opB(j,k)=B[j*ldb+k]; TB=0: opB(j,k)=B[k*ldb+j]
// If K1 >= 0, A loads with k >= K1 come from concatA[i*3 + (k-K1)] (stats).
template <int TA, int TB>
__global__ __launch_bounds__(256) void gemm_kernel(
    const float* __restrict__ A, int lda,
    const float* __restrict__ B, int ldb,
    float* __restrict__ C, int ldc,
    int M, int N, int K, float alpha,
    const float* __restrict__ concatA, int K1,
    const float* __restrict__ residual, int do_elu) {
  __shared__ __align__(16) float As[BK][BM + 4];
  __shared__ __align__(16) float Bs[BK][BN + 4];
  const int tid = threadIdx.x;
  const int bi = blockIdx.y * BM;
  const int bj = blockIdx.x * BN;
  const int tx = tid & 15;   // col group (4 cols each)
  const int ty = tid >> 4;   // row group (4 rows each)
  float acc[4][4] = {};

  for (int kk = 0; kk < K; kk += BK) {
    // ---- A tile -> As[k][i]
    if (TA == 0) {
      const int c = tid & 15;
      const int rb = tid >> 4;
#pragma unroll
      for (int it = 0; it < 4; ++it) {
        const int rr = rb + 16 * it;
        const int gi = bi + rr, gk = kk + c;
        float v = 0.f;
        if (gi < M && gk < K) {
          if (K1 >= 0 && gk >= K1) v = concatA[(size_t)gi * 3 + (gk - K1)];
          else v = A[(size_t)gi * lda + gk];
        }
        As[c][rr] = v;
      }
    } else {
      const int ii = tid & 63;
      const int kb = tid >> 6;
#pragma unroll
      for (int it = 0; it < 4; ++it) {
        const int k2 = kb * 4 + it;
        const int gi = bi + ii, gk = kk + k2;
        float v = 0.f;
        if (gi < M && gk < K) v = A[(size_t)gk * lda + gi];
        As[k2][ii] = v;
      }
    }
    // ---- B tile -> Bs[k][j]
    if (TB == 1) {
      const int c = tid & 15;
      const int jb = tid >> 4;
#pragma unroll
      for (int it = 0; it < 4; ++it) {
        const int jj = jb + 16 * it;
        const int gj = bj + jj, gk = kk + c;
        float v = 0.f;
        if (gj < N && gk < K) v = B[(size_t)gj * ldb + gk];
        Bs[c][jj] = v;
      }
    } else {
      const int jj = tid & 63;
      const int kb = tid >> 6;
#pragma unroll
      for (int it = 0; it < 4; ++it) {
        const int k2 = kb * 4 + it;
        const int gj = bj + jj, gk = kk + k2;
        float v = 0.f;
        if (gj < N && gk < K) v = B[(size_t)gk * ldb + gj];
        Bs[k2][jj] = v;
      }
    }
    __syncthreads();
#pragma unroll
    for (int k2 = 0; k2 < BK; ++k2) {
      const float4 av = *reinterpret_cast<const float4*>(&As[k2][ty * 4]);
      const float4 bv = *reinterpret_cast<const float4*>(&Bs[k2][tx * 4]);
      const float aa[4] = {av.x, av.y, av.z, av.w};
      const float bb[4] = {bv.x, bv.y, bv.z, bv.w};
#pragma unroll
      for (int ua = 0; ua < 4; ++ua)
#pragma unroll
        for (int ub = 0; ub < 4; ++ub)
          acc[ua][ub] = fmaf(aa[ua], bb[ub], acc[ua][ub]);
    }
    __syncthreads();
  }
  // ---- epilogue
#pragma unroll
  for (int ua = 0; ua < 4; ++ua) {
    const int gi = bi + ty * 4 + ua;
    if (gi >= M) continue;
#pragma unroll
    for (int ub = 0; ub < 4; ++ub) {
      const int gj = bj + tx * 4 + ub;
      if (gj >= N) continue;
      float v = acc[ua][ub] * alpha;
      if (do_elu) v = (v > 0.f) ? v : expm1f(v);
      if (residual) v += residual[(size_t)gi * ldc + gj];
      C[(size_t)gi * ldc + gj] = v;
    }
  }
}

// ---------------- row softmax + stats + 2x2 mixing combine ----------------
// In:  S = (k q^T)/16 raw scores,  X = a_x.
// Out: S <- a_h2 = m01*a_x + m11*a_h ;  X <- a_x2 = m00*a_x + m10*a_h.
// stats[r] = {a_x[r][r], rowsum(a_x), rowstd(a_x, ddof=1)}
__global__ __launch_bounds__(256) void row_combine_kernel(
    float* __restrict__ S, float* __restrict__ X,
    const float* __restrict__ mixing, float* __restrict__ stats, int n) {
  __shared__ float redM[4], redS[4], redX[4], redQ[4];
  const int r = blockIdx.x;
  const int t = threadIdx.x;
  const size_t rowoff = (size_t)r * n;
  const int wid = t >> 6, lane = t & 63;

  float sv[16], xv[16];
  float lmax = -1e30f;
#pragma unroll
  for (int u = 0; u < 16; ++u) {
    sv[u] = S[rowoff + t + 256 * u];
    lmax = fmaxf(lmax, sv[u]);
  }
  lmax = wave_reduce_max(lmax);
  if (lane == 0) redM[wid] = lmax;
  __syncthreads();
  const float gmax = fmaxf(fmaxf(redM[0], redM[1]), fmaxf(redM[2], redM[3]));

  float lsum = 0.f, xs = 0.f, xq = 0.f;
#pragma unroll
  for (int u = 0; u < 16; ++u) {
    sv[u] = expf(sv[u] - gmax);
    lsum += sv[u];
    xv[u] = X[rowoff + t + 256 * u];
    xs += xv[u];
    xq += xv[u] * xv[u];
  }
  lsum = wave_reduce_sum(lsum);
  xs = wave_reduce_sum(xs);
  xq = wave_reduce_sum(xq);
  if (lane == 0) { redS[wid] = lsum; redX[wid] = xs; redQ[wid] = xq; }
  __syncthreads();
  const float psum = redS[0] + redS[1] + redS[2] + redS[3];
  const float xsum = redX[0] + redX[1] + redX[2] + redX[3];
  const float xsq  = redQ[0] + redQ[1] + redQ[2] + redQ[3];
  const float pinv = 1.f / psum;

  // mixing: softmax over axis 0 (within each column)
  const float e00 = expf(mixing[0]), e10 = expf(mixing[2]);
  const float e01 = expf(mixing[1]), e11 = expf(mixing[3]);
  const float m00 = e00 / (e00 + e10), m10 = e10 / (e00 + e10);
  const float m01 = e01 / (e01 + e11), m11 = e11 / (e01 + e11);

  if ((r & 255) == t) {
    const float diag = xv[r >> 8];
    const float mean = xsum / (float)n;
    const float var = (xsq - (float)n * mean * mean) / (float)(n - 1);
    stats[(size_t)r * 3 + 0] = diag;
    stats[(size_t)r * 3 + 1] = xsum;
    stats[(size_t)r * 3 + 2] = sqrtf(fmaxf(var, 0.f));
  }

#pragma unroll
  for (int u = 0; u < 16; ++u) {
    const float p = sv[u] * pinv;
    const float xvv = xv[u];
    X[rowoff + t + 256 * u] = m00 * xvv + m10 * p;  // a_x2
    S[rowoff + t + 256 * u] = m01 * xvv + m11 * p;  // a_h2
  }
}

// --------------------------------------------------------------------------
extern "C" void kernel_launch(void* const* d_in, const int* in_sizes, int n_in,
                              void* d_out, int out_size, void* d_ws, size_t ws_size,
                              hipStream_t stream) {
  const float* h      = (const float*)d_in[0];
  const float* x      = (const float*)d_in[1];
  const float* w_k    = (const float*)d_in[2];
  const float* w_q    = (const float*)d_in[3];
  const float* w_v    = (const float*)d_in[4];
  const float* mixing = (const float*)d_in[5];
  const float* gamma  = (const float*)d_in[6];
  const float* beta   = (const float*)d_in[7];

  float* out_h = (float*)d_out;                       // h_out + h0   [N,F]
  float* out_x = out_h + (size_t)N_NODES * FDIM;      // x_out + x0   [N,F]

  const size_t NF = (size_t)N_NODES * FDIM;
  const size_t NN = (size_t)N_NODES * N_NODES;
  float* ws    = (float*)d_ws;
  float* hn    = ws;
  float* xn    = hn + NF;
  float* kb    = xn + NF;
  float* qb    = kb + NF;
  float* hagg  = qb + NF;
  float* stats = hagg + NF;
  float* S     = stats + 3 * N_NODES;   // raw scores -> a_h2     [N,N]
  float* X     = S + NN;                // a_x        -> a_x2     [N,N]

  rownorm_kernel<<<N_NODES, 256, 0, stream>>>(h, x, gamma, beta, hn, xn);

  dim3 gsmall(FDIM / BN, N_NODES / BM);     // (4, 64)
  dim3 gbig(N_NODES / BN, N_NODES / BM);    // (64, 64)

  // k = hn @ w_k^T ; q = hn @ w_q^T
  gemm_kernel<0, 1><<<gsmall, 256, 0, stream>>>(hn, FDIM, w_k, FDIM, kb, FDIM,
      N_NODES, FDIM, FDIM, 1.f, nullptr, -1, nullptr, 0);
  gemm_kernel<0, 1><<<gsmall, 256, 0, stream>>>(hn, FDIM, w_q, FDIM, qb, FDIM,
      N_NODES, FDIM, FDIM, 1.f, nullptr, -1, nullptr, 0);

  // S = (k @ q^T) / sqrt(F) ; X = xn @ xn^T
  gemm_kernel<0, 1><<<gbig, 256, 0, stream>>>(kb, FDIM, qb, FDIM, S, N_NODES,
      N_NODES, N_NODES, FDIM, 0.0625f, nullptr, -1, nullptr, 0);
  gemm_kernel<0, 1><<<gbig, 256, 0, stream>>>(xn, FDIM, xn, FDIM, X, N_NODES,
      N_NODES, N_NODES, FDIM, 1.f, nullptr, -1, nullptr, 0);

  // softmax(S) + stats + mixing:  X <- a_x2, S <- a_h2
  row_combine_kernel<<<N_NODES, 256, 0, stream>>>(S, X, mixing, stats, N_NODES);

  // x_out = a_x2 @ xn + x0
  gemm_kernel<0, 0><<<gsmall, 256, 0, stream>>>(X, N_NODES, xn, FDIM, out_x, FDIM,
      N_NODES, FDIM, N_NODES, 1.f, nullptr, -1, x, 0);

  // h_agg = a_h2^T @ hn
  gemm_kernel<1, 0><<<gsmall, 256, 0, stream>>>(S, N_NODES, hn, FDIM, hagg, FDIM,
      N_NODES, FDIM, N_NODES, 1.f, nullptr, -1, nullptr, 0);

  // h_out = elu(concat(h_agg, stats) @ w_v^T) + h0
  gemm_kernel<0, 1><<<gsmall, 256, 0, stream>>>(hagg, FDIM, w_v, FDIM + 3, out_h, FDIM,
      N_NODES, FDIM, FDIM + 3, 1.f, stats, FDIM, h, 1);
}

// Round 2
// 219.774 us; speedup vs baseline: 7.6769x; 7.6769x over previous
//
#include <hip/hip_runtime.h>
#include <cstdint>
#include <cstddef>

#define NB 4096
#define FD 256

typedef __attribute__((ext_vector_type(4))) float f32x4;
typedef __attribute__((ext_vector_type(8))) short bf16x8;

// ---------------- bf16 helpers (round-to-nearest-even) --------------------
__device__ __forceinline__ ushort f2bf(float f) {
  union { float f; uint32_t u; } v; v.f = f;
  uint32_t r = v.u + 0x7fffu + ((v.u >> 16) & 1u);
  return (ushort)(r >> 16);
}
__device__ __forceinline__ float bf2f(ushort b) {
  union { uint32_t u; float f; } v; v.u = ((uint32_t)b) << 16;
  return v.f;
}

// async global -> LDS, 16B per lane (wave-uniform LDS base + lane*16)
__device__ __forceinline__ void gld16(const void* g, void* l) {
  __builtin_amdgcn_global_load_lds(
      (const __attribute__((address_space(1))) char*)g,
      (__attribute__((address_space(3))) char*)l, 16, 0, 0);
}

__device__ __forceinline__ float wave_reduce_sum(float v) {
#pragma unroll
  for (int off = 32; off >= 1; off >>= 1) v += __shfl_xor(v, off);
  return v;
}
__device__ __forceinline__ float wave_reduce_max(float v) {
#pragma unroll
  for (int off = 32; off >= 1; off >>= 1) v = fmaxf(v, __shfl_xor(v, off));
  return v;
}

// ---------------- rownorm: LayerNorm(h)->bf16, L1norm(x)->bf16, diag ------
__global__ __launch_bounds__(256) void rownorm_kernel(
    const float* __restrict__ h, const float* __restrict__ x,
    const float* __restrict__ gamma, const float* __restrict__ beta,
    ushort* __restrict__ hnb, ushort* __restrict__ xnb, float* __restrict__ diag) {
  __shared__ float rA[4], rB[4], rC[4], rD[4];
  const int r = blockIdx.x, t = threadIdx.x, wid = t >> 6, lane = t & 63;
  const size_t base = (size_t)r * FD + t;
  const float hv = h[base], xv = x[base];
  float s1 = wave_reduce_sum(hv);
  float s2 = wave_reduce_sum(hv * hv);
  float a1 = wave_reduce_sum(fabsf(xv));
  float q1 = wave_reduce_sum(xv * xv);
  if (lane == 0) { rA[wid] = s1; rB[wid] = s2; rC[wid] = a1; rD[wid] = q1; }
  __syncthreads();
  const float S1 = rA[0] + rA[1] + rA[2] + rA[3];
  const float S2 = rB[0] + rB[1] + rB[2] + rB[3];
  const float L1 = rC[0] + rC[1] + rC[2] + rC[3];
  const float Q1 = rD[0] + rD[1] + rD[2] + rD[3];
  const float mu = S1 * (1.0f / FD);
  const float var = S2 * (1.0f / FD) - mu * mu;
  const float rstd = rsqrtf(var + 1e-5f);
  const float d = fmaxf(L1, 1e-12f), dinv = 1.0f / d;
  hnb[base] = f2bf((hv - mu) * rstd * gamma[t] + beta[t]);
  xnb[base] = f2bf(xv * dinv);
  if (t == 0) diag[r] = Q1 * dinv * dinv;
}

// ---------------- weight casts (w_v padded to K=320) ----------------------
__global__ __launch_bounds__(256) void wcast_kernel(
    const float* __restrict__ w_k, const float* __restrict__ w_q,
    const float* __restrict__ w_v,
    ushort* __restrict__ wkb, ushort* __restrict__ wqb, ushort* __restrict__ wvb) {
  const int r = blockIdx.x, t = threadIdx.x;
  wkb[r * 256 + t] = f2bf(w_k[r * 256 + t]);
  wqb[r * 256 + t] = f2bf(w_q[r * 256 + t]);
  wvb[r * 320 + t] = f2bf(w_v[(size_t)r * 259 + t]);  // t<256 < 259 always valid
  if (t < 64) {
    const int c = 256 + t;
    wvb[r * 320 + c] = (c < 259) ? f2bf(w_v[(size_t)r * 259 + c]) : (ushort)0;
  }
}

// ---------------- bf16 transpose, 64x64 tiles -----------------------------
__global__ __launch_bounds__(256) void transpose_kernel(
    const ushort* __restrict__ in, ushort* __restrict__ out, int R, int C) {
  __shared__ ushort tile[64][65];
  const int bc = blockIdx.x * 64, br = blockIdx.y * 64;
  const int t = threadIdx.x;
#pragma unroll
  for (int i = 0; i < 16; ++i) {
    const int idx = t + 256 * i;
    const int rr = idx >> 6, cc = idx & 63;
    tile[rr][cc] = in[(size_t)(br + rr) * C + bc + cc];
  }
  __syncthreads();
#pragma unroll
  for (int i = 0; i < 16; ++i) {
    const int idx = t + 256 * i;
    const int rr = idx >> 6, cc = idx & 63;
    out[(size_t)(bc + rr) * R + br + cc] = tile[cc][rr];
  }
}

// ---------------- colsum of xn (from xnT, coalesced) ----------------------
__global__ __launch_bounds__(256) void colsum_kernel(
    const ushort* __restrict__ xnT, float* __restrict__ s) {
  __shared__ float red[4];
  const int f = blockIdx.x, t = threadIdx.x, wid = t >> 6, lane = t & 63;
  float a = 0.f;
#pragma unroll
  for (int i = 0; i < 16; ++i) a += bf2f(xnT[(size_t)f * NB + t + 256 * i]);
  a = wave_reduce_sum(a);
  if (lane == 0) red[wid] = a;
  __syncthreads();
  if (t == 0) s[f] = red[0] + red[1] + red[2] + red[3];
}

// ---------------- split-K partial reduce (16 segs) ------------------------
__global__ __launch_bounds__(256) void reduce16_kernel(
    const float* __restrict__ in, ushort* __restrict__ out) {
  const int idx = blockIdx.x * 256 + threadIdx.x;
  float a = 0.f;
#pragma unroll
  for (int z = 0; z < 16; ++z) a += in[(size_t)z * (FD * FD) + idx];
  out[idx] = f2bf(a);
}

// ---------------- row softmax: S (fp32) -> P (bf16, normalized) -----------
__global__ __launch_bounds__(256) void softmax_kernel(
    const float* __restrict__ S, ushort* __restrict__ P) {
  __shared__ float red[4];
  const int r = blockIdx.x, t = threadIdx.x, wid = t >> 6, lane = t & 63;
  const float4* Sr = (const float4*)(S + (size_t)r * NB);
  float4 v[4];
  float lmax = -1e30f;
#pragma unroll
  for (int i = 0; i < 4; ++i) {
    v[i] = Sr[t + 256 * i];
    lmax = fmaxf(lmax, fmaxf(fmaxf(v[i].x, v[i].y), fmaxf(v[i].z, v[i].w)));
  }
  lmax = wave_reduce_max(lmax);
  if (lane == 0) red[wid] = lmax;
  __syncthreads();
  const float gmax = fmaxf(fmaxf(red[0], red[1]), fmaxf(red[2], red[3]));
  __syncthreads();
  float lsum = 0.f;
#pragma unroll
  for (int i = 0; i < 4; ++i) {
    v[i].x = __expf(v[i].x - gmax); v[i].y = __expf(v[i].y - gmax);
    v[i].z = __expf(v[i].z - gmax); v[i].w = __expf(v[i].w - gmax);
    lsum += v[i].x + v[i].y + v[i].z + v[i].w;
  }
  lsum = wave_reduce_sum(lsum);
  if (lane == 0) red[wid] = lsum;
  __syncthreads();
  const float pinv = 1.f / (red[0] + red[1] + red[2] + red[3]);
  ushort4* Pr = (ushort4*)(P + (size_t)r * NB);
#pragma unroll
  for (int i = 0; i < 4; ++i) {
    ushort4 o;
    o.x = f2bf(v[i].x * pinv); o.y = f2bf(v[i].y * pinv);
    o.z = f2bf(v[i].z * pinv); o.w = f2bf(v[i].w * pinv);
    Pr[t + 256 * i] = o;
  }
}

// ---------------- stats row pass -> hagg_pad cols 256..319 ----------------
__global__ __launch_bounds__(64) void stats_kernel(
    const ushort* __restrict__ xnb, const float* __restrict__ t2,
    const float* __restrict__ s, const float* __restrict__ diag,
    ushort* __restrict__ haggp) {
  const int r = blockIdx.x, l = threadIdx.x;
  float rs = 0.f, rq = 0.f;
#pragma unroll
  for (int i = 0; i < 4; ++i) {
    const int f = l + 64 * i;
    const float xv = bf2f(xnb[(size_t)r * FD + f]);
    rs += xv * s[f];
    rq += xv * t2[(size_t)r * FD + f];
  }
  rs = wave_reduce_sum(rs);
  rq = wave_reduce_sum(rq);
  const float mean = rs * (1.0f / NB);
  const float var = (rq - (float)NB * mean * mean) * (1.0f / (NB - 1));
  const float sd = sqrtf(fmaxf(var, 0.f));
  ushort v = 0;
  if (l == 0) v = f2bf(diag[r]);
  else if (l == 1) v = f2bf(rs);
  else if (l == 2) v = f2bf(sd);
  haggp[(size_t)r * 320 + 256 + l] = v;  // l=0..2 stats, 3..63 zeros (pad)
}

// ---------------- NT bf16 MFMA GEMM: C[i,j] = sum_k A[i,k]*B[j,k] ---------
// EPI: 0 fp32*alpha | 1 bf16*alpha | 2 x_out: mB*acc+mA*R1+R2 (fp32)
//      3 hagg: bf16(mB*acc+mA*R1) | 4 final: fp32 elu(acc)+R2 | 5 splitK fp32
template <int BM, int BN, int EPI>
__global__ __launch_bounds__(256) void gemm_nt(
    const ushort* __restrict__ A, int lda,
    const ushort* __restrict__ B, int ldb,
    void* __restrict__ Cp, int ldc, int K, float alpha,
    const float* __restrict__ mix,
    const float* __restrict__ R1, const float* __restrict__ R2) {
  constexpr int WM = BM / 2, WN = BN / 2, MR = WM / 16, NR = WN / 16;
  __shared__ __align__(16) ushort At[BM][32];
  __shared__ __align__(16) ushort Bt[BN][32];
  const int tid = threadIdx.x;
  const int wave = tid >> 6, lane = tid & 63;
  const int wr = wave >> 1, wc = wave & 1;
  const int bi = blockIdx.y * BM, bj = blockIdx.x * BN;
  const int fr = lane & 15, fq = lane >> 4;
  const int srow = lane >> 2, skoff = (lane & 3) * 8;

  f32x4 acc[MR][NR];
#pragma unroll
  for (int m = 0; m < MR; ++m)
#pragma unroll
    for (int n = 0; n < NR; ++n) acc[m][n] = (f32x4){0.f, 0.f, 0.f, 0.f};

  const int kbase = (EPI == 5) ? blockIdx.z * K : 0;
  for (int k0 = kbase; k0 < kbase + K; k0 += 32) {
    for (int c = wave; c < BM / 16; c += 4)
      gld16(A + (size_t)(bi + c * 16 + srow) * lda + k0 + skoff, &At[c * 16][0]);
    for (int c = wave; c < BN / 16; c += 4)
      gld16(B + (size_t)(bj + c * 16 + srow) * ldb + k0 + skoff, &Bt[c * 16][0]);
    __syncthreads();
    bf16x8 a[MR], b[NR];
#pragma unroll
    for (int m = 0; m < MR; ++m)
      a[m] = *(const bf16x8*)&At[wr * WM + m * 16 + fr][fq * 8];
#pragma unroll
    for (int n = 0; n < NR; ++n)
      b[n] = *(const bf16x8*)&Bt[wc * WN + n * 16 + fr][fq * 8];
#pragma unroll
    for (int m = 0; m < MR; ++m)
#pragma unroll
      for (int n = 0; n < NR; ++n)
        acc[m][n] = __builtin_amdgcn_mfma_f32_16x16x32_bf16(a[m], b[n], acc[m][n], 0, 0, 0);
    __syncthreads();
  }

  float mA = 0.f, mB = alpha;
  if (EPI == 2) { const float eA = __expf(mix[0]), eB = __expf(mix[2]); mA = eA / (eA + eB); mB = eB / (eA + eB); }
  if (EPI == 3) { const float eA = __expf(mix[1]), eB = __expf(mix[3]); mA = eA / (eA + eB); mB = eB / (eA + eB); }

#pragma unroll
  for (int m = 0; m < MR; ++m)
#pragma unroll
    for (int n = 0; n < NR; ++n)
#pragma unroll
      for (int r = 0; r < 4; ++r) {
        const int row = bi + wr * WM + m * 16 + fq * 4 + r;
        const int col = bj + wc * WN + n * 16 + fr;
        const size_t ci = (size_t)row * ldc + col;
        const size_t ri = (size_t)row * FD + col;
        const float v = acc[m][n][r];
        if (EPI == 0) ((float*)Cp)[ci] = v * alpha;
        else if (EPI == 1) ((ushort*)Cp)[ci] = f2bf(v * alpha);
        else if (EPI == 2) ((float*)Cp)[ci] = mB * v + mA * R1[ri] + R2[ri];
        else if (EPI == 3) ((ushort*)Cp)[ci] = f2bf(mB * v + mA * R1[ri]);
        else if (EPI == 4) { const float e = (v > 0.f) ? v : expm1f(v); ((float*)Cp)[ci] = e + R2[ri]; }
        else if (EPI == 5) ((float*)Cp)[(size_t)blockIdx.z * (FD * FD) + ci] = v;
      }
}

// --------------------------------------------------------------------------
extern "C" void kernel_launch(void* const* d_in, const int* in_sizes, int n_in,
                              void* d_out, int out_size, void* d_ws, size_t ws_size,
                              hipStream_t stream) {
  const float* h      = (const float*)d_in[0];
  const float* x      = (const float*)d_in[1];
  const float* w_k    = (const float*)d_in[2];
  const float* w_q    = (const float*)d_in[3];
  const float* w_v    = (const float*)d_in[4];
  const float* mixing = (const float*)d_in[5];
  const float* gamma  = (const float*)d_in[6];
  const float* beta   = (const float*)d_in[7];

  float* out_h = (float*)d_out;
  float* out_x = out_h + (size_t)NB * FD;

  char* w = (char*)d_ws;
  float*  S     = (float*)(w + 0);            // 64MB   [NB,NB] fp32 scores
  ushort* P     = (ushort*)(w + 67108864);    // 32MB   a_h bf16
  ushort* hnb   = (ushort*)(w + 100663296);   // 2MB
  ushort* xnb   = (ushort*)(w + 102760448);   // 2MB
  ushort* hnbT  = (ushort*)(w + 104857600);   // 2MB    [FD,NB]
  ushort* xnbT  = (ushort*)(w + 106954752);   // 2MB    [FD,NB]
  ushort* kb    = (ushort*)(w + 109051904);   // 2MB
  ushort* qb    = (ushort*)(w + 111149056);   // 2MB
  ushort* haggp = (ushort*)(w + 113246208);   // 2.5MB  [NB,320]
  ushort* wkb   = (ushort*)(w + 115867648);
  ushort* wqb   = (ushort*)(w + 115998720);
  ushort* wvb   = (ushort*)(w + 116129792);   // [FD,320]
  ushort* Gb    = (ushort*)(w + 116293632);   // [FD,FD]
  ushort* M2b   = (ushort*)(w + 116424704);   // [FD,FD]
  float*  diag  = (float*)(w + 116555776);    // [NB]
  float*  sv    = (float*)(w + 116572160);    // [FD]
  // aliases into the S region (lifetimes disjoint from S / each other):
  float*  Gp  = (float*)(w + 0);              // split-K partials (dead before S)
  float*  M2p = (float*)(w + 4194304);
  ushort* PT  = (ushort*)(w + 0);             // 32MB (after softmax, S dead)
  float*  t2  = (float*)(w + 33554432);       // 4MB  a_x@xn
  float*  t3  = (float*)(w + 37748736);       // 4MB  a_x@hn

  rownorm_kernel<<<NB, 256, 0, stream>>>(h, x, gamma, beta, hnb, xnb, diag);
  wcast_kernel<<<FD, 256, 0, stream>>>(w_k, w_q, w_v, wkb, wqb, wvb);
  transpose_kernel<<<dim3(FD / 64, NB / 64), 256, 0, stream>>>(xnb, xnbT, NB, FD);
  transpose_kernel<<<dim3(FD / 64, NB / 64), 256, 0, stream>>>(hnb, hnbT, NB, FD);
  colsum_kernel<<<FD, 256, 0, stream>>>(xnbT, sv);

  // projections: k = hn @ w_k^T, q = hn @ w_q^T (bf16 out)
  gemm_nt<64, 64, 1><<<dim3(FD / 64, NB / 64), 256, 0, stream>>>(
      hnb, FD, wkb, FD, kb, FD, FD, 1.f, nullptr, nullptr, nullptr);
  gemm_nt<64, 64, 1><<<dim3(FD / 64, NB / 64), 256, 0, stream>>>(
      hnb, FD, wqb, FD, qb, FD, FD, 1.f, nullptr, nullptr, nullptr);

  // Gram matrices, split-K=16: G = xn^T@xn, M2 = hn^T@xn
  gemm_nt<64, 64, 5><<<dim3(4, 4, 16), 256, 0, stream>>>(
      xnbT, NB, xnbT, NB, Gp, FD, NB / 16, 1.f, nullptr, nullptr, nullptr);
  gemm_nt<64, 64, 5><<<dim3(4, 4, 16), 256, 0, stream>>>(
      hnbT, NB, xnbT, NB, M2p, FD, NB / 16, 1.f, nullptr, nullptr, nullptr);
  reduce16_kernel<<<FD * FD / 256, 256, 0, stream>>>(Gp, Gb);
  reduce16_kernel<<<FD * FD / 256, 256, 0, stream>>>(M2p, M2b);

  // S = (k @ q^T) / 16
  gemm_nt<128, 128, 0><<<dim3(NB / 128, NB / 128), 256, 0, stream>>>(
      kb, FD, qb, FD, S, NB, FD, 0.0625f, nullptr, nullptr, nullptr);
  softmax_kernel<<<NB, 256, 0, stream>>>(S, P);
  transpose_kernel<<<dim3(NB / 64, NB / 64), 256, 0, stream>>>(P, PT, NB, NB);

  // t2 = xn@G (= a_x@xn), t3 = xn@M2 (= a_x@hn)  (fp32 out)
  gemm_nt<64, 64, 0><<<dim3(FD / 64, NB / 64), 256, 0, stream>>>(
      xnb, FD, Gb, FD, t2, FD, FD, 1.f, nullptr, nullptr, nullptr);
  gemm_nt<64, 64, 0><<<dim3(FD / 64, NB / 64), 256, 0, stream>>>(
      xnb, FD, M2b, FD, t3, FD, FD, 1.f, nullptr, nullptr, nullptr);

  // stats -> hagg_pad cols 256..319
  stats_kernel<<<NB, 64, 0, stream>>>(xnb, t2, sv, diag, haggp);

  // x_out = m10*(P@xn) + m00*t2 + x
  gemm_nt<64, 32, 2><<<dim3(FD / 32, NB / 64), 256, 0, stream>>>(
      P, NB, xnbT, NB, out_x, FD, NB, 1.f, mixing, t2, x);
  // hagg = m11*(P^T@hn) + m01*t3 (bf16 into padded [NB,320])
  gemm_nt<64, 32, 3><<<dim3(FD / 32, NB / 64), 256, 0, stream>>>(
      PT, NB, hnbT, NB, haggp, 320, NB, 1.f, mixing, t3, nullptr);
  // h_out = elu(concat(hagg,stats) @ w_v^T) + h
  gemm_nt<64, 64, 4><<<dim3(FD / 64, NB / 64), 256, 0, stream>>>(
      haggp, 320, wvb, 320, out_h, FD, 320, 1.f, nullptr, nullptr, h);
}

// Round 3
// 198.642 us; speedup vs baseline: 8.4936x; 1.1064x over previous
//
#include <hip/hip_runtime.h>
#include <cstdint>
#include <cstddef>

#define NB 4096
#define FD 256

typedef __attribute__((ext_vector_type(4))) float f32x4;
typedef __attribute__((ext_vector_type(8))) short bf16x8;

__device__ __forceinline__ ushort f2bf(float f) {
  union { float f; uint32_t u; } v; v.f = f;
  uint32_t r = v.u + 0x7fffu + ((v.u >> 16) & 1u);
  return (ushort)(r >> 16);
}
__device__ __forceinline__ float bf2f(ushort b) {
  union { uint32_t u; float f; } v; v.u = ((uint32_t)b) << 16;
  return v.f;
}

__device__ __forceinline__ void gld16(const void* g, void* l) {
  __builtin_amdgcn_global_load_lds(
      (const __attribute__((address_space(1))) char*)g,
      (__attribute__((address_space(3))) char*)l, 16, 0, 0);
}

__device__ __forceinline__ float wave_reduce_sum(float v) {
#pragma unroll
  for (int off = 32; off >= 1; off >>= 1) v += __shfl_xor(v, off);
  return v;
}
__device__ __forceinline__ float wave_reduce_max(float v) {
#pragma unroll
  for (int off = 32; off >= 1; off >>= 1) v = fmaxf(v, __shfl_xor(v, off));
  return v;
}

// ---------------- rownorm ---------------------------------------------------
__global__ __launch_bounds__(256) void rownorm_kernel(
    const float* __restrict__ h, const float* __restrict__ x,
    const float* __restrict__ gamma, const float* __restrict__ beta,
    ushort* __restrict__ hnb, ushort* __restrict__ xnb, float* __restrict__ diag) {
  __shared__ float rA[4], rB[4], rC[4], rD[4];
  const int r = blockIdx.x, t = threadIdx.x, wid = t >> 6, lane = t & 63;
  const size_t base = (size_t)r * FD + t;
  const float hv = h[base], xv = x[base];
  float s1 = wave_reduce_sum(hv);
  float s2 = wave_reduce_sum(hv * hv);
  float a1 = wave_reduce_sum(fabsf(xv));
  float q1 = wave_reduce_sum(xv * xv);
  if (lane == 0) { rA[wid] = s1; rB[wid] = s2; rC[wid] = a1; rD[wid] = q1; }
  __syncthreads();
  const float S1 = rA[0] + rA[1] + rA[2] + rA[3];
  const float S2 = rB[0] + rB[1] + rB[2] + rB[3];
  const float L1 = rC[0] + rC[1] + rC[2] + rC[3];
  const float Q1 = rD[0] + rD[1] + rD[2] + rD[3];
  const float mu = S1 * (1.0f / FD);
  const float var = S2 * (1.0f / FD) - mu * mu;
  const float rstd = rsqrtf(var + 1e-5f);
  const float d = fmaxf(L1, 1e-12f), dinv = 1.0f / d;
  hnb[base] = f2bf((hv - mu) * rstd * gamma[t] + beta[t]);
  xnb[base] = f2bf(xv * dinv);
  if (t == 0) diag[r] = Q1 * dinv * dinv;
}

// ---------------- weight casts ---------------------------------------------
__global__ __launch_bounds__(256) void wcast_kernel(
    const float* __restrict__ w_k, const float* __restrict__ w_q,
    const float* __restrict__ w_v,
    ushort* __restrict__ wkb, ushort* __restrict__ wqb, ushort* __restrict__ wvb) {
  const int r = blockIdx.x, t = threadIdx.x;
  wkb[r * 256 + t] = f2bf(w_k[r * 256 + t]);
  wqb[r * 256 + t] = f2bf(w_q[r * 256 + t]);
  wvb[r * 320 + t] = f2bf(w_v[(size_t)r * 259 + t]);
  if (t < 64) {
    const int c = 256 + t;
    wvb[r * 320 + c] = (c < 259) ? f2bf(w_v[(size_t)r * 259 + c]) : (ushort)0;
  }
}

// ---------------- bf16 transpose (64x64 tiles) ------------------------------
__global__ __launch_bounds__(256) void transpose_kernel(
    const ushort* __restrict__ in, ushort* __restrict__ out, int R, int C) {
  __shared__ ushort tile[64][65];
  const int bc = blockIdx.x * 64, br = blockIdx.y * 64;
  const int t = threadIdx.x;
#pragma unroll
  for (int i = 0; i < 16; ++i) {
    const int idx = t + 256 * i;
    const int rr = idx >> 6, cc = idx & 63;
    tile[rr][cc] = in[(size_t)(br + rr) * C + bc + cc];
  }
  __syncthreads();
#pragma unroll
  for (int i = 0; i < 16; ++i) {
    const int idx = t + 256 * i;
    const int rr = idx >> 6, cc = idx & 63;
    out[(size_t)(bc + rr) * R + br + cc] = tile[cc][rr];
  }
}

// ---------------- colsum of xn ----------------------------------------------
__global__ __launch_bounds__(256) void colsum_kernel(
    const ushort* __restrict__ xnT, float* __restrict__ s) {
  __shared__ float red[4];
  const int f = blockIdx.x, t = threadIdx.x, wid = t >> 6, lane = t & 63;
  float a = 0.f;
#pragma unroll
  for (int i = 0; i < 16; ++i) a += bf2f(xnT[(size_t)f * NB + t + 256 * i]);
  a = wave_reduce_sum(a);
  if (lane == 0) red[wid] = a;
  __syncthreads();
  if (t == 0) s[f] = red[0] + red[1] + red[2] + red[3];
}

// ---------------- split-K 16-way reduce (Gram) ------------------------------
__global__ __launch_bounds__(256) void reduce16_kernel(
    const float* __restrict__ in, ushort* __restrict__ out) {
  const int idx = blockIdx.x * 256 + threadIdx.x;
  float a = 0.f;
#pragma unroll
  for (int z = 0; z < 16; ++z) a += in[(size_t)z * (FD * FD) + idx];
  out[idx] = f2bf(a);
}

// ---------------- row softmax: S bf16 -> P bf16 -----------------------------
__global__ __launch_bounds__(256) void softmax_kernel(
    const ushort* __restrict__ S, ushort* __restrict__ P) {
  __shared__ float red[4];
  const int r = blockIdx.x, t = threadIdx.x, wid = t >> 6, lane = t & 63;
  const uint4* Sr = (const uint4*)(S + (size_t)r * NB);
  float v[16];
  float lmax = -1e30f;
#pragma unroll
  for (int i = 0; i < 2; ++i) {
    const uint4 c = Sr[t + 256 * i];
    const uint32_t w4[4] = {c.x, c.y, c.z, c.w};
#pragma unroll
    for (int j = 0; j < 4; ++j) {
      v[i * 8 + j * 2]     = bf2f((ushort)(w4[j] & 0xffffu));
      v[i * 8 + j * 2 + 1] = bf2f((ushort)(w4[j] >> 16));
    }
  }
#pragma unroll
  for (int u = 0; u < 16; ++u) lmax = fmaxf(lmax, v[u]);
  lmax = wave_reduce_max(lmax);
  if (lane == 0) red[wid] = lmax;
  __syncthreads();
  const float gmax = fmaxf(fmaxf(red[0], red[1]), fmaxf(red[2], red[3]));
  __syncthreads();
  float lsum = 0.f;
#pragma unroll
  for (int u = 0; u < 16; ++u) { v[u] = __expf(v[u] - gmax); lsum += v[u]; }
  lsum = wave_reduce_sum(lsum);
  if (lane == 0) red[wid] = lsum;
  __syncthreads();
  const float pinv = 1.f / (red[0] + red[1] + red[2] + red[3]);
  uint4* Pr = (uint4*)(P + (size_t)r * NB);
#pragma unroll
  for (int i = 0; i < 2; ++i) {
    uint4 o;
    o.x = (uint32_t)f2bf(v[i*8+0] * pinv) | ((uint32_t)f2bf(v[i*8+1] * pinv) << 16);
    o.y = (uint32_t)f2bf(v[i*8+2] * pinv) | ((uint32_t)f2bf(v[i*8+3] * pinv) << 16);
    o.z = (uint32_t)f2bf(v[i*8+4] * pinv) | ((uint32_t)f2bf(v[i*8+5] * pinv) << 16);
    o.w = (uint32_t)f2bf(v[i*8+6] * pinv) | ((uint32_t)f2bf(v[i*8+7] * pinv) << 16);
    Pr[t + 256 * i] = o;
  }
}

// ---------------- stats -> haggp cols 256..319 ------------------------------
__global__ __launch_bounds__(64) void stats_kernel(
    const ushort* __restrict__ xnb, const float* __restrict__ t2,
    const float* __restrict__ s, const float* __restrict__ diag,
    ushort* __restrict__ haggp) {
  const int r = blockIdx.x, l = threadIdx.x;
  float rs = 0.f, rq = 0.f;
#pragma unroll
  for (int i = 0; i < 4; ++i) {
    const int f = l + 64 * i;
    const float xv = bf2f(xnb[(size_t)r * FD + f]);
    rs += xv * s[f];
    rq += xv * t2[(size_t)r * FD + f];
  }
  rs = wave_reduce_sum(rs);
  rq = wave_reduce_sum(rq);
  const float mean = rs * (1.0f / NB);
  const float var = (rq - (float)NB * mean * mean) * (1.0f / (NB - 1));
  const float sd = sqrtf(fmaxf(var, 0.f));
  ushort v = 0;
  if (l == 0) v = f2bf(diag[r]);
  else if (l == 1) v = f2bf(rs);
  else if (l == 2) v = f2bf(sd);
  haggp[(size_t)r * 320 + 256 + l] = v;
}

// ---------------- combine: split-K partials + mixing + residual -------------
// MODE 0: out_x(fp32) = mB*(p0+p1) + mA*R1 + R2
// MODE 1: haggp(bf16, ld 320) = mB*(p0+p1) + mA*R1
template <int MODE>
__global__ __launch_bounds__(256) void combine_kernel(
    const float* __restrict__ p, const float* __restrict__ R1,
    const float* __restrict__ R2, float* __restrict__ outF,
    ushort* __restrict__ outB, const float* __restrict__ mix) {
  const size_t NF = (size_t)NB * FD;
  const size_t idx = ((size_t)blockIdx.x * 256 + threadIdx.x) * 4;
  const float eA = __expf(mix[MODE == 0 ? 0 : 1]);
  const float eB = __expf(mix[MODE == 0 ? 2 : 3]);
  const float mA = eA / (eA + eB), mB = eB / (eA + eB);
  const float4 p0 = *(const float4*)(p + idx);
  const float4 p1 = *(const float4*)(p + NF + idx);
  const float4 r1 = *(const float4*)(R1 + idx);
  float acc[4] = {p0.x + p1.x, p0.y + p1.y, p0.z + p1.z, p0.w + p1.w};
  if (MODE == 0) {
    const float4 r2 = *(const float4*)(R2 + idx);
    const float rr1[4] = {r1.x, r1.y, r1.z, r1.w};
    const float rr2[4] = {r2.x, r2.y, r2.z, r2.w};
    float4 o;
    o.x = mB * acc[0] + mA * rr1[0] + rr2[0];
    o.y = mB * acc[1] + mA * rr1[1] + rr2[1];
    o.z = mB * acc[2] + mA * rr1[2] + rr2[2];
    o.w = mB * acc[3] + mA * rr1[3] + rr2[3];
    *(float4*)(outF + idx) = o;
  } else {
    const float rr1[4] = {r1.x, r1.y, r1.z, r1.w};
    const size_t row = idx >> 8, col = idx & 255;
    ushort4 o;
    o.x = f2bf(mB * acc[0] + mA * rr1[0]);
    o.y = f2bf(mB * acc[1] + mA * rr1[1]);
    o.z = f2bf(mB * acc[2] + mA * rr1[2]);
    o.w = f2bf(mB * acc[3] + mA * rr1[3]);
    *(ushort4*)(outB + row * 320 + col) = o;
  }
}

// ---------------- NT bf16 MFMA GEMM -----------------------------------------
// C[i,j] = sum_k A[i,k]*B[j,k]
// EPI: 0 fp32*alpha | 1 bf16*alpha | 4 fp32 elu(acc)+R2 | 5 splitK fp32 partial
template <int BM, int BN, int EPI>
__global__ __launch_bounds__(256) void gemm_nt(
    const ushort* __restrict__ A, int lda,
    const ushort* __restrict__ B, int ldb,
    void* __restrict__ Cp, int ldc, int K, float alpha,
    size_t pstride, const float* __restrict__ R2) {
  constexpr int WAVES_N = (BM <= 32) ? 4 : 2;
  constexpr int WAVES_M = 4 / WAVES_N;
  constexpr int WM = BM / WAVES_M, WN = BN / WAVES_N;
  constexpr int MR = WM / 16, NR = WN / 16;
  __shared__ __align__(16) ushort At[BM][32];
  __shared__ __align__(16) ushort Bt[BN][32];
  const int tid = threadIdx.x;
  const int wave = tid >> 6, lane = tid & 63;
  const int wr = wave / WAVES_N, wc = wave % WAVES_N;
  const int bi = blockIdx.y * BM, bj = blockIdx.x * BN;
  const int fr = lane & 15, fq = lane >> 4;
  const int srow = lane >> 2, skoff = (lane & 3) * 8;

  f32x4 acc[MR][NR];
#pragma unroll
  for (int m = 0; m < MR; ++m)
#pragma unroll
    for (int n = 0; n < NR; ++n) acc[m][n] = (f32x4){0.f, 0.f, 0.f, 0.f};

  const int kbase = (EPI == 5) ? blockIdx.z * K : 0;
  for (int k0 = kbase; k0 < kbase + K; k0 += 32) {
    for (int c = wave; c < BM / 16; c += 4)
      gld16(A + (size_t)(bi + c * 16 + srow) * lda + k0 + skoff, &At[c * 16][0]);
    for (int c = wave; c < BN / 16; c += 4)
      gld16(B + (size_t)(bj + c * 16 + srow) * ldb + k0 + skoff, &Bt[c * 16][0]);
    __syncthreads();
    bf16x8 a[MR], b[NR];
#pragma unroll
    for (int m = 0; m < MR; ++m)
      a[m] = *(const bf16x8*)&At[wr * WM + m * 16 + fr][fq * 8];
#pragma unroll
    for (int n = 0; n < NR; ++n)
      b[n] = *(const bf16x8*)&Bt[wc * WN + n * 16 + fr][fq * 8];
#pragma unroll
    for (int m = 0; m < MR; ++m)
#pragma unroll
      for (int n = 0; n < NR; ++n)
        acc[m][n] = __builtin_amdgcn_mfma_f32_16x16x32_bf16(a[m], b[n], acc[m][n], 0, 0, 0);
    __syncthreads();
  }

#pragma unroll
  for (int m = 0; m < MR; ++m)
#pragma unroll
    for (int n = 0; n < NR; ++n)
#pragma unroll
      for (int r = 0; r < 4; ++r) {
        const int row = bi + wr * WM + m * 16 + fq * 4 + r;
        const int col = bj + wc * WN + n * 16 + fr;
        const size_t ci = (size_t)row * ldc + col;
        const float v = acc[m][n][r];
        if (EPI == 0) ((float*)Cp)[ci] = v * alpha;
        else if (EPI == 1) ((ushort*)Cp)[ci] = f2bf(v * alpha);
        else if (EPI == 4) { const float e = (v > 0.f) ? v : expm1f(v); ((float*)Cp)[ci] = e + R2[(size_t)row * FD + col]; }
        else if (EPI == 5) ((float*)Cp)[(size_t)blockIdx.z * pstride + ci] = v;
      }
}

// ---------------------------------------------------------------------------
extern "C" void kernel_launch(void* const* d_in, const int* in_sizes, int n_in,
                              void* d_out, int out_size, void* d_ws, size_t ws_size,
                              hipStream_t stream) {
  const float* h      = (const float*)d_in[0];
  const float* x      = (const float*)d_in[1];
  const float* w_k    = (const float*)d_in[2];
  const float* w_q    = (const float*)d_in[3];
  const float* w_v    = (const float*)d_in[4];
  const float* mixing = (const float*)d_in[5];
  const float* gamma  = (const float*)d_in[6];
  const float* beta   = (const float*)d_in[7];

  float* out_h = (float*)d_out;
  float* out_x = out_h + (size_t)NB * FD;

  char* w = (char*)d_ws;
  ushort* S     = (ushort*)(w + 0);           // 32MB [NB,NB] bf16 scores
  ushort* P     = (ushort*)(w + 33554432);    // 32MB
  ushort* PT    = (ushort*)(w + 67108864);    // 32MB
  ushort* hnb   = (ushort*)(w + 100663296);
  ushort* xnb   = (ushort*)(w + 102760448);
  ushort* hnbT  = (ushort*)(w + 104857600);
  ushort* xnbT  = (ushort*)(w + 106954752);
  ushort* kb    = (ushort*)(w + 109051904);
  ushort* qb    = (ushort*)(w + 111149056);
  ushort* haggp = (ushort*)(w + 113246208);   // [NB,320] bf16
  ushort* wkb   = (ushort*)(w + 115867648);
  ushort* wqb   = (ushort*)(w + 115998720);
  ushort* wvb   = (ushort*)(w + 116129792);   // [FD,320]
  ushort* Gb    = (ushort*)(w + 116293632);
  ushort* M2b   = (ushort*)(w + 116424704);
  float*  diag  = (float*)(w + 116555776);
  float*  sv    = (float*)(w + 116572160);
  float*  t2    = (float*)(w + 116573184);    // 4MB
  float*  t3    = (float*)(w + 120767488);    // 4MB
  // aliases (disjoint lifetimes):
  float*  Gp  = (float*)(w + 67108864);       // in PT region, dead before PT
  float*  M2p = (float*)(w + 71303168);
  float*  px  = (float*)(w + 0);              // in S region, S dead after softmax
  float*  ph  = (float*)(w + 16777216);

  rownorm_kernel<<<NB, 256, 0, stream>>>(h, x, gamma, beta, hnb, xnb, diag);
  wcast_kernel<<<FD, 256, 0, stream>>>(w_k, w_q, w_v, wkb, wqb, wvb);
  transpose_kernel<<<dim3(FD / 64, NB / 64), 256, 0, stream>>>(xnb, xnbT, NB, FD);
  transpose_kernel<<<dim3(FD / 64, NB / 64), 256, 0, stream>>>(hnb, hnbT, NB, FD);
  colsum_kernel<<<FD, 256, 0, stream>>>(xnbT, sv);

  // projections
  gemm_nt<64, 64, 1><<<dim3(FD / 64, NB / 64), 256, 0, stream>>>(
      hnb, FD, wkb, FD, kb, FD, FD, 1.f, 0, nullptr);
  gemm_nt<64, 64, 1><<<dim3(FD / 64, NB / 64), 256, 0, stream>>>(
      hnb, FD, wqb, FD, qb, FD, FD, 1.f, 0, nullptr);

  // Gram matrices (split-K 16)
  gemm_nt<64, 64, 5><<<dim3(4, 4, 16), 256, 0, stream>>>(
      xnbT, NB, xnbT, NB, Gp, FD, NB / 16, 1.f, (size_t)FD * FD, nullptr);
  gemm_nt<64, 64, 5><<<dim3(4, 4, 16), 256, 0, stream>>>(
      hnbT, NB, xnbT, NB, M2p, FD, NB / 16, 1.f, (size_t)FD * FD, nullptr);
  reduce16_kernel<<<FD * FD / 256, 256, 0, stream>>>(Gp, Gb);
  reduce16_kernel<<<FD * FD / 256, 256, 0, stream>>>(M2p, M2b);

  // S = bf16((k @ q^T) / 16)
  gemm_nt<128, 128, 1><<<dim3(NB / 128, NB / 128), 256, 0, stream>>>(
      kb, FD, qb, FD, S, NB, FD, 0.0625f, 0, nullptr);
  softmax_kernel<<<NB, 256, 0, stream>>>(S, P);
  transpose_kernel<<<dim3(NB / 64, NB / 64), 256, 0, stream>>>(P, PT, NB, NB);

  // t2 = xn@G, t3 = xn@M2
  gemm_nt<64, 64, 0><<<dim3(FD / 64, NB / 64), 256, 0, stream>>>(
      xnb, FD, Gb, FD, t2, FD, FD, 1.f, 0, nullptr);
  gemm_nt<64, 64, 0><<<dim3(FD / 64, NB / 64), 256, 0, stream>>>(
      xnb, FD, M2b, FD, t3, FD, FD, 1.f, 0, nullptr);
  stats_kernel<<<NB, 64, 0, stream>>>(xnb, t2, sv, diag, haggp);

  // aggregation partials (split-K 2, 512 blocks each)
  gemm_nt<32, 128, 5><<<dim3(FD / 128, NB / 32, 2), 256, 0, stream>>>(
      P, NB, xnbT, NB, px, FD, NB / 2, 1.f, (size_t)NB * FD, nullptr);
  gemm_nt<32, 128, 5><<<dim3(FD / 128, NB / 32, 2), 256, 0, stream>>>(
      PT, NB, hnbT, NB, ph, FD, NB / 2, 1.f, (size_t)NB * FD, nullptr);

  // combines: x_out, haggp[:,0:256]
  combine_kernel<0><<<NB * FD / 1024, 256, 0, stream>>>(px, t2, x, out_x, nullptr, mixing);
  combine_kernel<1><<<NB * FD / 1024, 256, 0, stream>>>(ph, t3, nullptr, nullptr, haggp, mixing);

  // h_out = elu(concat(hagg,stats) @ w_v^T) + h
  gemm_nt<64, 64, 4><<<dim3(FD / 64, NB / 64), 256, 0, stream>>>(
      haggp, 320, wvb, 320, out_h, FD, 320, 1.f, 0, h);
}

// Round 4
// 176.843 us; speedup vs baseline: 9.5406x; 1.1233x over previous
//
#include <hip/hip_runtime.h>
#include <cstdint>
#include <cstddef>

#define NB 4096
#define FD 256

typedef __attribute__((ext_vector_type(4))) float f32x4;
typedef __attribute__((ext_vector_type(8))) short bf16x8;

__device__ __forceinline__ ushort f2bf(float f) {
  union { float f; uint32_t u; } v; v.f = f;
  uint32_t r = v.u + 0x7fffu + ((v.u >> 16) & 1u);
  return (ushort)(r >> 16);
}
__device__ __forceinline__ float bf2f(ushort b) {
  union { uint32_t u; float f; } v; v.u = ((uint32_t)b) << 16;
  return v.f;
}

__device__ __forceinline__ void gld16(const void* g, void* l) {
  __builtin_amdgcn_global_load_lds(
      (const __attribute__((address_space(1))) char*)g,
      (__attribute__((address_space(3))) char*)l, 16, 0, 0);
}

__device__ __forceinline__ float wave_reduce_sum(float v) {
#pragma unroll
  for (int off = 32; off >= 1; off >>= 1) v += __shfl_xor(v, off);
  return v;
}
__device__ __forceinline__ float wave_reduce_max(float v) {
#pragma unroll
  for (int off = 32; off >= 1; off >>= 1) v = fmaxf(v, __shfl_xor(v, off));
  return v;
}

// ---------------- rownorm ---------------------------------------------------
__global__ __launch_bounds__(256) void rownorm_kernel(
    const float* __restrict__ h, const float* __restrict__ x,
    const float* __restrict__ gamma, const float* __restrict__ beta,
    ushort* __restrict__ hnb, ushort* __restrict__ xnb, float* __restrict__ diag) {
  __shared__ float rA[4], rB[4], rC[4], rD[4];
  const int r = blockIdx.x, t = threadIdx.x, wid = t >> 6, lane = t & 63;
  const size_t base = (size_t)r * FD + t;
  const float hv = h[base], xv = x[base];
  float s1 = wave_reduce_sum(hv);
  float s2 = wave_reduce_sum(hv * hv);
  float a1 = wave_reduce_sum(fabsf(xv));
  float q1 = wave_reduce_sum(xv * xv);
  if (lane == 0) { rA[wid] = s1; rB[wid] = s2; rC[wid] = a1; rD[wid] = q1; }
  __syncthreads();
  const float S1 = rA[0] + rA[1] + rA[2] + rA[3];
  const float S2 = rB[0] + rB[1] + rB[2] + rB[3];
  const float L1 = rC[0] + rC[1] + rC[2] + rC[3];
  const float Q1 = rD[0] + rD[1] + rD[2] + rD[3];
  const float mu = S1 * (1.0f / FD);
  const float var = S2 * (1.0f / FD) - mu * mu;
  const float rstd = rsqrtf(var + 1e-5f);
  const float d = fmaxf(L1, 1e-12f), dinv = 1.0f / d;
  hnb[base] = f2bf((hv - mu) * rstd * gamma[t] + beta[t]);
  xnb[base] = f2bf(xv * dinv);
  if (t == 0) diag[r] = Q1 * dinv * dinv;
}

// ---------------- weight casts ---------------------------------------------
__global__ __launch_bounds__(256) void wcast_kernel(
    const float* __restrict__ w_k, const float* __restrict__ w_q,
    const float* __restrict__ w_v,
    ushort* __restrict__ wkb, ushort* __restrict__ wqb, ushort* __restrict__ wvb) {
  const int r = blockIdx.x, t = threadIdx.x;
  wkb[r * 256 + t] = f2bf(w_k[r * 256 + t]);
  wqb[r * 256 + t] = f2bf(w_q[r * 256 + t]);
  wvb[r * 320 + t] = f2bf(w_v[(size_t)r * 259 + t]);
  if (t < 64) {
    const int c = 256 + t;
    wvb[r * 320 + c] = (c < 259) ? f2bf(w_v[(size_t)r * 259 + c]) : (ushort)0;
  }
}

// ---------------- bf16 transpose (64x64 tiles) ------------------------------
__global__ __launch_bounds__(256) void transpose_kernel(
    const ushort* __restrict__ in, ushort* __restrict__ out, int R, int C) {
  __shared__ ushort tile[64][65];
  const int bc = blockIdx.x * 64, br = blockIdx.y * 64;
  const int t = threadIdx.x;
#pragma unroll
  for (int i = 0; i < 16; ++i) {
    const int idx = t + 256 * i;
    const int rr = idx >> 6, cc = idx & 63;
    tile[rr][cc] = in[(size_t)(br + rr) * C + bc + cc];
  }
  __syncthreads();
#pragma unroll
  for (int i = 0; i < 16; ++i) {
    const int idx = t + 256 * i;
    const int rr = idx >> 6, cc = idx & 63;
    out[(size_t)(bc + rr) * R + br + cc] = tile[cc][rr];
  }
}

// ---------------- colsum of xn ----------------------------------------------
__global__ __launch_bounds__(256) void colsum_kernel(
    const ushort* __restrict__ xnT, float* __restrict__ s) {
  __shared__ float red[4];
  const int f = blockIdx.x, t = threadIdx.x, wid = t >> 6, lane = t & 63;
  float a = 0.f;
#pragma unroll
  for (int i = 0; i < 16; ++i) a += bf2f(xnT[(size_t)f * NB + t + 256 * i]);
  a = wave_reduce_sum(a);
  if (lane == 0) red[wid] = a;
  __syncthreads();
  if (t == 0) s[f] = red[0] + red[1] + red[2] + red[3];
}

// ---------------- split-K 16-way reduce (Gram) ------------------------------
__global__ __launch_bounds__(256) void reduce16_kernel(
    const float* __restrict__ in, ushort* __restrict__ out) {
  const int idx = blockIdx.x * 256 + threadIdx.x;
  float a = 0.f;
#pragma unroll
  for (int z = 0; z < 16; ++z) a += in[(size_t)z * (FD * FD) + idx];
  out[idx] = f2bf(a);
}

// ---------------- row softmax: S bf16 -> P bf16 -----------------------------
__global__ __launch_bounds__(256) void softmax_kernel(
    const ushort* __restrict__ S, ushort* __restrict__ P) {
  __shared__ float red[4];
  const int r = blockIdx.x, t = threadIdx.x, wid = t >> 6, lane = t & 63;
  const uint4* Sr = (const uint4*)(S + (size_t)r * NB);
  float v[16];
  float lmax = -1e30f;
#pragma unroll
  for (int i = 0; i < 2; ++i) {
    const uint4 c = Sr[t + 256 * i];
    const uint32_t w4[4] = {c.x, c.y, c.z, c.w};
#pragma unroll
    for (int j = 0; j < 4; ++j) {
      v[i * 8 + j * 2]     = bf2f((ushort)(w4[j] & 0xffffu));
      v[i * 8 + j * 2 + 1] = bf2f((ushort)(w4[j] >> 16));
    }
  }
#pragma unroll
  for (int u = 0; u < 16; ++u) lmax = fmaxf(lmax, v[u]);
  lmax = wave_reduce_max(lmax);
  if (lane == 0) red[wid] = lmax;
  __syncthreads();
  const float gmax = fmaxf(fmaxf(red[0], red[1]), fmaxf(red[2], red[3]));
  __syncthreads();
  float lsum = 0.f;
#pragma unroll
  for (int u = 0; u < 16; ++u) { v[u] = __expf(v[u] - gmax); lsum += v[u]; }
  lsum = wave_reduce_sum(lsum);
  if (lane == 0) red[wid] = lsum;
  __syncthreads();
  const float pinv = 1.f / (red[0] + red[1] + red[2] + red[3]);
  uint4* Pr = (uint4*)(P + (size_t)r * NB);
#pragma unroll
  for (int i = 0; i < 2; ++i) {
    uint4 o;
    o.x = (uint32_t)f2bf(v[i*8+0] * pinv) | ((uint32_t)f2bf(v[i*8+1] * pinv) << 16);
    o.y = (uint32_t)f2bf(v[i*8+2] * pinv) | ((uint32_t)f2bf(v[i*8+3] * pinv) << 16);
    o.z = (uint32_t)f2bf(v[i*8+4] * pinv) | ((uint32_t)f2bf(v[i*8+5] * pinv) << 16);
    o.w = (uint32_t)f2bf(v[i*8+6] * pinv) | ((uint32_t)f2bf(v[i*8+7] * pinv) << 16);
    Pr[t + 256 * i] = o;
  }
}

// ---------------- stats -> haggp cols 256..319 ------------------------------
__global__ __launch_bounds__(64) void stats_kernel(
    const ushort* __restrict__ xnb, const float* __restrict__ t2,
    const float* __restrict__ s, const float* __restrict__ diag,
    ushort* __restrict__ haggp) {
  const int r = blockIdx.x, l = threadIdx.x;
  float rs = 0.f, rq = 0.f;
#pragma unroll
  for (int i = 0; i < 4; ++i) {
    const int f = l + 64 * i;
    const float xv = bf2f(xnb[(size_t)r * FD + f]);
    rs += xv * s[f];
    rq += xv * t2[(size_t)r * FD + f];
  }
  rs = wave_reduce_sum(rs);
  rq = wave_reduce_sum(rq);
  const float mean = rs * (1.0f / NB);
  const float var = (rq - (float)NB * mean * mean) * (1.0f / (NB - 1));
  const float sd = sqrtf(fmaxf(var, 0.f));
  ushort v = 0;
  if (l == 0) v = f2bf(diag[r]);
  else if (l == 1) v = f2bf(rs);
  else if (l == 2) v = f2bf(sd);
  haggp[(size_t)r * 320 + 256 + l] = v;
}

// ---------------- fused combine: 8 bf16 partials each + mixing + residual ---
// out_x = mBx*sum(px) + mAx*t2 + x ;  haggp[:,0:256] = bf16(mBh*sum(ph) + mAh*t3)
__global__ __launch_bounds__(256) void combine_both_kernel(
    const ushort* __restrict__ px, const ushort* __restrict__ ph,
    const float* __restrict__ t2, const float* __restrict__ t3,
    const float* __restrict__ x, float* __restrict__ out_x,
    ushort* __restrict__ haggp, const float* __restrict__ mix) {
  const size_t NF = (size_t)NB * FD;
  const size_t idx = ((size_t)blockIdx.x * 256 + threadIdx.x) * 4;
  const float e0x = __expf(mix[0]), e1x = __expf(mix[2]);
  const float mAx = e0x / (e0x + e1x), mBx = e1x / (e0x + e1x);
  const float e0h = __expf(mix[1]), e1h = __expf(mix[3]);
  const float mAh = e0h / (e0h + e1h), mBh = e1h / (e0h + e1h);

  float ax[4] = {0.f, 0.f, 0.f, 0.f}, ah[4] = {0.f, 0.f, 0.f, 0.f};
#pragma unroll
  for (int z = 0; z < 8; ++z) {
    const ushort4 cx = *(const ushort4*)(px + (size_t)z * NF + idx);
    const ushort4 ch = *(const ushort4*)(ph + (size_t)z * NF + idx);
    ax[0] += bf2f(cx.x); ax[1] += bf2f(cx.y); ax[2] += bf2f(cx.z); ax[3] += bf2f(cx.w);
    ah[0] += bf2f(ch.x); ah[1] += bf2f(ch.y); ah[2] += bf2f(ch.z); ah[3] += bf2f(ch.w);
  }
  const float4 r2 = *(const float4*)(t2 + idx);
  const float4 r3 = *(const float4*)(t3 + idx);
  const float4 xr = *(const float4*)(x + idx);
  float4 ox;
  ox.x = mBx * ax[0] + mAx * r2.x + xr.x;
  ox.y = mBx * ax[1] + mAx * r2.y + xr.y;
  ox.z = mBx * ax[2] + mAx * r2.z + xr.z;
  ox.w = mBx * ax[3] + mAx * r2.w + xr.w;
  *(float4*)(out_x + idx) = ox;
  const size_t row = idx >> 8, col = idx & 255;
  ushort4 oh;
  oh.x = f2bf(mBh * ah[0] + mAh * r3.x);
  oh.y = f2bf(mBh * ah[1] + mAh * r3.y);
  oh.z = f2bf(mBh * ah[2] + mAh * r3.z);
  oh.w = f2bf(mBh * ah[3] + mAh * r3.w);
  *(ushort4*)(haggp + row * 320 + col) = oh;
}

// ---------------- NT bf16 MFMA GEMM, 2-phase double-buffered ----------------
// C[i,j] = sum_k A[i,k]*B[j,k]
// EPI: 0 fp32*alpha | 1 bf16*alpha | 4 fp32 elu(acc)+R2
//      5 splitK fp32 partial | 6 splitK bf16 partial
// LDS granule swizzle: slot(row,q) holds global granule (q ^ (row&3)); applied
// to BOTH the gld16 source address and the ds_read offset (both-sides rule).
template <int BM, int BN, int EPI>
__global__ __launch_bounds__(256) void gemm_nt(
    const ushort* __restrict__ A, int lda,
    const ushort* __restrict__ B, int ldb,
    void* __restrict__ Cp, int ldc, int K, float alpha,
    size_t pstride, const float* __restrict__ R2) {
  constexpr int WAVES_N = (BM <= 32) ? 4 : 2;
  constexpr int WAVES_M = 4 / WAVES_N;
  constexpr int WM = BM / WAVES_M, WN = BN / WAVES_N;
  constexpr int MR = WM / 16, NR = WN / 16;
  __shared__ __align__(16) ushort At[2][BM][32];
  __shared__ __align__(16) ushort Bt[2][BN][32];
  const int tid = threadIdx.x;
  const int wave = tid >> 6, lane = tid & 63;
  const int wr = wave / WAVES_N, wc = wave % WAVES_N;
  const int bi = blockIdx.y * BM, bj = blockIdx.x * BN;
  const int fr = lane & 15, fq = lane >> 4;
  const int sub = lane >> 2, q = lane & 3;

  f32x4 acc[MR][NR];
#pragma unroll
  for (int m = 0; m < MR; ++m)
#pragma unroll
    for (int n = 0; n < NR; ++n) acc[m][n] = (f32x4){0.f, 0.f, 0.f, 0.f};

  const int kbase = (EPI >= 5) ? (int)blockIdx.z * K : 0;
  const int kend = kbase + K;

  // stage one 32-wide k-tile into buffer `bufi` (source pre-swizzled)
  auto stage = [&](int bufi, int k0) {
    for (int c = wave; c < BM / 16; c += 4) {
      const int row = c * 16 + sub;
      const int qs = q ^ (row & 3);
      gld16(A + (size_t)(bi + row) * lda + k0 + qs * 8, &At[bufi][c * 16][0]);
    }
    for (int c = wave; c < BN / 16; c += 4) {
      const int row = c * 16 + sub;
      const int qs = q ^ (row & 3);
      gld16(B + (size_t)(bj + row) * ldb + k0 + qs * 8, &Bt[bufi][c * 16][0]);
    }
  };

  stage(0, kbase);
  __syncthreads();

  int cur = 0;
  for (int k0 = kbase; k0 < kend; k0 += 32) {
    if (k0 + 32 < kend) stage(cur ^ 1, k0 + 32);  // prefetch next tile
    bf16x8 a[MR], b[NR];
#pragma unroll
    for (int m = 0; m < MR; ++m) {
      const int row = wr * WM + m * 16 + fr;
      a[m] = *(const bf16x8*)((const char*)&At[cur][row][0] + ((fq ^ (row & 3)) * 16));
    }
#pragma unroll
    for (int n = 0; n < NR; ++n) {
      const int row = wc * WN + n * 16 + fr;
      b[n] = *(const bf16x8*)((const char*)&Bt[cur][row][0] + ((fq ^ (row & 3)) * 16));
    }
#pragma unroll
    for (int m = 0; m < MR; ++m)
#pragma unroll
      for (int n = 0; n < NR; ++n)
        acc[m][n] = __builtin_amdgcn_mfma_f32_16x16x32_bf16(a[m], b[n], acc[m][n], 0, 0, 0);
    __syncthreads();  // drains vmcnt (prefetch landed) + lgkm; next iter reads cur^1
    cur ^= 1;
  }

#pragma unroll
  for (int m = 0; m < MR; ++m)
#pragma unroll
    for (int n = 0; n < NR; ++n)
#pragma unroll
      for (int r = 0; r < 4; ++r) {
        const int row = bi + wr * WM + m * 16 + fq * 4 + r;
        const int col = bj + wc * WN + n * 16 + fr;
        const size_t ci = (size_t)row * ldc + col;
        const float v = acc[m][n][r];
        if (EPI == 0) ((float*)Cp)[ci] = v * alpha;
        else if (EPI == 1) ((ushort*)Cp)[ci] = f2bf(v * alpha);
        else if (EPI == 4) { const float e = (v > 0.f) ? v : expm1f(v); ((float*)Cp)[ci] = e + R2[(size_t)row * FD + col]; }
        else if (EPI == 5) ((float*)Cp)[(size_t)blockIdx.z * pstride + ci] = v;
        else if (EPI == 6) ((ushort*)Cp)[(size_t)blockIdx.z * pstride + ci] = f2bf(v);
      }
}

// ---------------------------------------------------------------------------
extern "C" void kernel_launch(void* const* d_in, const int* in_sizes, int n_in,
                              void* d_out, int out_size, void* d_ws, size_t ws_size,
                              hipStream_t stream) {
  const float* h      = (const float*)d_in[0];
  const float* x      = (const float*)d_in[1];
  const float* w_k    = (const float*)d_in[2];
  const float* w_q    = (const float*)d_in[3];
  const float* w_v    = (const float*)d_in[4];
  const float* mixing = (const float*)d_in[5];
  const float* gamma  = (const float*)d_in[6];
  const float* beta   = (const float*)d_in[7];

  float* out_h = (float*)d_out;
  float* out_x = out_h + (size_t)NB * FD;

  char* w = (char*)d_ws;
  ushort* S     = (ushort*)(w + 0);           // 32MB [NB,NB] bf16 scores
  ushort* P     = (ushort*)(w + 33554432);    // 32MB
  ushort* PT    = (ushort*)(w + 67108864);    // 32MB
  ushort* hnb   = (ushort*)(w + 100663296);
  ushort* xnb   = (ushort*)(w + 102760448);
  ushort* hnbT  = (ushort*)(w + 104857600);
  ushort* xnbT  = (ushort*)(w + 106954752);
  ushort* kb    = (ushort*)(w + 109051904);
  ushort* qb    = (ushort*)(w + 111149056);
  ushort* haggp = (ushort*)(w + 113246208);   // [NB,320] bf16
  ushort* wkb   = (ushort*)(w + 115867648);
  ushort* wqb   = (ushort*)(w + 115998720);
  ushort* wvb   = (ushort*)(w + 116129792);   // [FD,320]
  ushort* Gb    = (ushort*)(w + 116293632);
  ushort* M2b   = (ushort*)(w + 116424704);
  float*  diag  = (float*)(w + 116555776);
  float*  sv    = (float*)(w + 116572160);
  float*  t2    = (float*)(w + 116573184);    // 4MB
  float*  t3    = (float*)(w + 120767488);    // 4MB
  // aliases (disjoint lifetimes):
  float*  Gp  = (float*)(w + 67108864);       // in PT region, dead before PT
  float*  M2p = (float*)(w + 71303168);
  ushort* px  = (ushort*)(w + 0);             // 16MB, in S region (S dead after softmax)
  ushort* ph  = (ushort*)(w + 16777216);      // 16MB

  rownorm_kernel<<<NB, 256, 0, stream>>>(h, x, gamma, beta, hnb, xnb, diag);
  wcast_kernel<<<FD, 256, 0, stream>>>(w_k, w_q, w_v, wkb, wqb, wvb);
  transpose_kernel<<<dim3(FD / 64, NB / 64), 256, 0, stream>>>(xnb, xnbT, NB, FD);
  transpose_kernel<<<dim3(FD / 64, NB / 64), 256, 0, stream>>>(hnb, hnbT, NB, FD);
  colsum_kernel<<<FD, 256, 0, stream>>>(xnbT, sv);

  // projections
  gemm_nt<64, 64, 1><<<dim3(FD / 64, NB / 64), 256, 0, stream>>>(
      hnb, FD, wkb, FD, kb, FD, FD, 1.f, 0, nullptr);
  gemm_nt<64, 64, 1><<<dim3(FD / 64, NB / 64), 256, 0, stream>>>(
      hnb, FD, wqb, FD, qb, FD, FD, 1.f, 0, nullptr);

  // Gram matrices (split-K 16, fp32 partials)
  gemm_nt<64, 64, 5><<<dim3(4, 4, 16), 256, 0, stream>>>(
      xnbT, NB, xnbT, NB, Gp, FD, NB / 16, 1.f, (size_t)FD * FD, nullptr);
  gemm_nt<64, 64, 5><<<dim3(4, 4, 16), 256, 0, stream>>>(
      hnbT, NB, xnbT, NB, M2p, FD, NB / 16, 1.f, (size_t)FD * FD, nullptr);
  reduce16_kernel<<<FD * FD / 256, 256, 0, stream>>>(Gp, Gb);
  reduce16_kernel<<<FD * FD / 256, 256, 0, stream>>>(M2p, M2b);

  // S = bf16((k @ q^T) / 16)
  gemm_nt<128, 128, 1><<<dim3(NB / 128, NB / 128), 256, 0, stream>>>(
      kb, FD, qb, FD, S, NB, FD, 0.0625f, 0, nullptr);
  softmax_kernel<<<NB, 256, 0, stream>>>(S, P);
  transpose_kernel<<<dim3(NB / 64, NB / 64), 256, 0, stream>>>(P, PT, NB, NB);

  // t2 = xn@G, t3 = xn@M2
  gemm_nt<64, 64, 0><<<dim3(FD / 64, NB / 64), 256, 0, stream>>>(
      xnb, FD, Gb, FD, t2, FD, FD, 1.f, 0, nullptr);
  gemm_nt<64, 64, 0><<<dim3(FD / 64, NB / 64), 256, 0, stream>>>(
      xnb, FD, M2b, FD, t3, FD, FD, 1.f, 0, nullptr);
  stats_kernel<<<NB, 64, 0, stream>>>(xnb, t2, sv, diag, haggp);

  // aggregation partials (split-K 8, bf16 partials, 2048 blocks each)
  gemm_nt<32, 128, 6><<<dim3(FD / 128, NB / 32, 8), 256, 0, stream>>>(
      P, NB, xnbT, NB, px, FD, NB / 8, 1.f, (size_t)NB * FD, nullptr);
  gemm_nt<32, 128, 6><<<dim3(FD / 128, NB / 32, 8), 256, 0, stream>>>(
      PT, NB, hnbT, NB, ph, FD, NB / 8, 1.f, (size_t)NB * FD, nullptr);

  // fused combine: x_out and haggp[:,0:256]
  combine_both_kernel<<<NB * FD / 1024, 256, 0, stream>>>(
      px, ph, t2, t3, x, out_x, haggp, mixing);

  // h_out = elu(concat(hagg,stats) @ w_v^T) + h
  gemm_nt<64, 64, 4><<<dim3(FD / 64, NB / 64), 256, 0, stream>>>(
      haggp, 320, wvb, 320, out_h, FD, 320, 1.f, 0, h);
}